// Round 1
// baseline (3446.914 us; speedup 1.0000x reference)
//
#include <hip/hip_runtime.h>

typedef unsigned short u16;
typedef short short8 __attribute__((ext_vector_type(8)));
typedef float f32x4 __attribute__((ext_vector_type(4)));
typedef unsigned int u32x4 __attribute__((ext_vector_type(4)));
typedef unsigned short u16x4 __attribute__((ext_vector_type(4)));

#define Bsz 32
#define Tsz 512
#define Dsz 1024
#define Usz 1024
#define Gsz 4096   // 4*U

// ---- bf16 helpers (manual RNE) ----
static __device__ __forceinline__ u16 f2bf(float f) {
    unsigned int u = __float_as_uint(f);
    unsigned int lsb = (u >> 16) & 1u;
    u += 0x7fffu + lsb;
    return (u16)(u >> 16);
}
static __device__ __forceinline__ float bf2f(u16 b) {
    return __uint_as_float(((unsigned int)b) << 16);
}

// =====================================================================
// Pack kernels: MFMA-fragment-ordered bf16 buffers.
// A-frag (16x16x32): lane L holds A[m = mt*16 + (L&15)][k = kb*32 + (L>>4)*8 + j]
// B-frag:            lane L holds B[k = kb*32 + (L>>4)*8 + j][n = nt*16 + (L&15)]
// Flat: buf[((tile*32 + kb)*64 + L)*8 + j] -> lane-contiguous 16B chunks.
// =====================================================================

__global__ __launch_bounds__(256) void pack_a(const float* __restrict__ x, u16* __restrict__ Af) {
    size_t tid = (size_t)blockIdx.x * 256 + threadIdx.x;
    int L = (int)(tid & 63);
    size_t mtkb = tid >> 6;
    int kb = (int)(mtkb & 31);
    int mt = (int)(mtkb >> 5);
    int m  = mt * 16 + (L & 15);
    int d0 = kb * 32 + (L >> 4) * 8;
    const float* src = x + (size_t)m * Dsz + d0;
    short8 v;
#pragma unroll
    for (int j = 0; j < 8; ++j) v[j] = (short)f2bf(src[j]);
    *(short8*)(Af + tid * 8) = v;
}

__global__ __launch_bounds__(256) void pack_b(const float* __restrict__ W, u16* __restrict__ Bf) {
    size_t tid = (size_t)blockIdx.x * 256 + threadIdx.x;
    int L = (int)(tid & 63);
    size_t ntkb = tid >> 6;
    int kb = (int)(ntkb & 31);
    int nt = (int)(ntkb >> 5);
    int n  = nt * 16 + (L & 15);
    int k0 = kb * 32 + (L >> 4) * 8;
    short8 v;
#pragma unroll
    for (int j = 0; j < 8; ++j) v[j] = (short)f2bf(W[(size_t)(k0 + j) * Gsz + n]);
    *(short8*)(Bf + tid * 8) = v;
}

// R -> Rp block-major gate-interleaved for the 64-block scan:
// tile t_g (0..255) covers u = (t_g>>2)*16 + (t_g&3)*4 + du, packed col c
// within tile: gate = c>>2, du = c&3.  scan block blk owns tiles blk*4..+3.
// Also zeroes the barrier flags (ws is poisoned 0xAA before every call!).
__global__ __launch_bounds__(256) void pack_r(const float* __restrict__ R, u16* __restrict__ Rp,
                                              unsigned* __restrict__ flags) {
    if (blockIdx.x == 0) flags[threadIdx.x] = 0;
    size_t tid = (size_t)blockIdx.x * 256 + threadIdx.x;
    int L = (int)(tid & 63);
    size_t tkb = tid >> 6;
    int kb   = (int)(tkb & 31);
    int tile = (int)(tkb >> 5);          // 0..255
    int c = L & 15;
    int g = (c >> 2) * 1024 + (tile >> 2) * 16 + (tile & 3) * 4 + (c & 3);
    int k0 = kb * 32 + (L >> 4) * 8;
    short8 v;
#pragma unroll
    for (int j = 0; j < 8; ++j) v[j] = (short)f2bf(R[(size_t)(k0 + j) * Gsz + g]);
    *(short8*)(Rp + tid * 8) = v;
}

// =====================================================================
// GEMM1: x_proj = X @ W; 128x128 tile, 4 waves. Epilogue writes the
// scan layout: [t][blk(64)][b(32)][ul(16)][gate(4)] so each scan thread
// reads exactly one float4/u16x4 per (t,b,ul).
// =====================================================================
__global__ __launch_bounds__(256) void gemm1(const u16* __restrict__ Af, const u16* __restrict__ Bf,
                                             float* __restrict__ xpf, u16* __restrict__ xph, int xp32) {
    __shared__ u16 smem[16 * 512];
    int bm = blockIdx.x >> 5;
    int bn = blockIdx.x & 31;
    int tid = threadIdx.x;
    int w = tid >> 6, ln = tid & 63;
    int mw = w & 1, nw = w >> 1;

    f32x4 acc[4][4];
#pragma unroll
    for (int i = 0; i < 4; ++i)
#pragma unroll
        for (int j = 0; j < 4; ++j) acc[i][j] = (f32x4){0.f, 0.f, 0.f, 0.f};

    for (int kb = 0; kb < 32; ++kb) {
        short8 tmp[4];
#pragma unroll
        for (int c2 = 0; c2 < 4; ++c2) {
            int chunk = w * 4 + c2;
            const u16* src = (chunk < 8)
                ? Af + (((size_t)(bm * 8 + chunk) * 32 + kb) * 64 + ln) * 8
                : Bf + (((size_t)(bn * 8 + (chunk - 8)) * 32 + kb) * 64 + ln) * 8;
            tmp[c2] = *(const short8*)src;
        }
#pragma unroll
        for (int c2 = 0; c2 < 4; ++c2) {
            int chunk = w * 4 + c2;
            *(short8*)(smem + chunk * 512 + ln * 8) = tmp[c2];
        }
        __syncthreads();
        short8 av[4], bv[4];
#pragma unroll
        for (int i = 0; i < 4; ++i) av[i] = *(const short8*)(smem + (mw * 4 + i) * 512 + ln * 8);
#pragma unroll
        for (int j = 0; j < 4; ++j) bv[j] = *(const short8*)(smem + (8 + nw * 4 + j) * 512 + ln * 8);
#pragma unroll
        for (int i = 0; i < 4; ++i)
#pragma unroll
            for (int j = 0; j < 4; ++j)
                acc[i][j] = __builtin_amdgcn_mfma_f32_16x16x32_bf16(av[i], bv[j], acc[i][j], 0, 0, 0);
        __syncthreads();
    }

    int quad = ln >> 4, c15 = ln & 15;
#pragma unroll
    for (int i = 0; i < 4; ++i) {
        int mt_g = bm * 8 + mw * 4 + i;
#pragma unroll
        for (int j = 0; j < 4; ++j) {
            int g = (bn * 8 + nw * 4 + j) * 16 + c15;   // original W column
            int gate = g >> 10;
            int u = g & 1023;
            int blkw = u >> 4, ulw = u & 15;
#pragma unroll
            for (int r = 0; r < 4; ++r) {
                int row = mt_g * 16 + quad * 4 + r;
                int bb = row >> 9, tt = row & 511;
                size_t o = ((size_t)tt * 64 + blkw) * 2048 + (size_t)bb * 64 + (size_t)(ulw * 4 + gate);
                if (xp32) xpf[o] = acc[i][j][r];
                else      xph[o] = f2bf(acc[i][j][r]);
            }
        }
    }
}

// =====================================================================
// Scan: 64 blocks x 512 threads (8 waves).  Wave = (mt in 2, kh in 4):
// rows mt*16..+15, K-slice kh*256..+255, ALL 4 n-tiles of the block.
// R fragments are loop-invariant in VGPRs (128 regs) -> zero LDS reads
// in the matmul; each (mt,kh) h-fragment is read by exactly ONE wave,
// so per-step LLC h traffic is 64 x 64KB = 4MB (was 16MB).
// Protocol (unchanged semantics): poll flags >= t+1 -> bypass-load
// h_{t-1} -> MFMA -> LDS kh-reduce -> gates -> bypass-store h_t ->
// vmcnt(0)/barrier -> flag = t+2.  Double-buffered h, one-sided flags.
// =====================================================================
__global__ __launch_bounds__(512) void scan_all(const float* __restrict__ xpf,
                                                const u16* __restrict__ xph, int xp32,
                                                const u16* __restrict__ Rp,
                                                const float* __restrict__ bias,
                                                u16* __restrict__ hbf, float* __restrict__ out,
                                                unsigned* __restrict__ flags) {
    __shared__ f32x4 partial[6][4][64];   // [(kh-1)*2+mt][tile][lane]
    __shared__ float proj[32 * 4 * 17];   // (b*4+gate)*17 + ul

    int tid = threadIdx.x;
    int blk = blockIdx.x;
    int w = tid >> 6, ln = tid & 63, quad = ln >> 4, c15 = ln & 15;
    int mt = w & 1, kh = w >> 1;
    int b_row = tid >> 4, ul = tid & 15;
    int u_g = blk * 16 + ul;

    u16* hb0 = hbf;                       // written at even t
    u16* hb1 = hbf + 32 * 1024;           // written at odd t; zeros for t=0

    // ---- loop-invariant B (R) fragments into registers: 4 tiles x 8 kb ----
    short8 rB[32];
#pragma unroll
    for (int j = 0; j < 4; ++j)
#pragma unroll
        for (int kbl = 0; kbl < 8; ++kbl)
            rB[j * 8 + kbl] =
                *(const short8*)(Rp + (((size_t)(blk * 4 + j) * 32 + (size_t)(kh * 8 + kbl)) * 64 + ln) * 8);

    float bi0 = bias[u_g], bi1 = bias[1024 + u_g], bi2 = bias[2048 + u_g], bi3 = bias[3072 + u_g];
    float cs = 0.f, ns = 0.f, ms = 0.f;
    float xpn0, xpn1, xpn2, xpn3;

    {   // h_{-1} = 0 in hb1 (bypass store -> LLC); t=0 x_proj prefetch
        u16* hp = hb1 + b_row * Usz + u_g;
        unsigned z = 0;
        asm volatile("global_store_short %0, %1, off sc0 sc1" :: "v"(hp), "v"(z) : "memory");
        size_t o0 = (size_t)blk * 2048 + (size_t)b_row * 64 + (size_t)(ul * 4);
        if (xp32) { float4 v4 = *(const float4*)(xpf + o0); xpn0 = v4.x; xpn1 = v4.y; xpn2 = v4.z; xpn3 = v4.w; }
        else      { u16x4 v = *(const u16x4*)(xph + o0); xpn0 = bf2f(v[0]); xpn1 = bf2f(v[1]); xpn2 = bf2f(v[2]); xpn3 = bf2f(v[3]); }
    }
    asm volatile("s_waitcnt vmcnt(0)" ::: "memory");
    __syncthreads();
    if (tid == 0) {
        unsigned* fp = flags + blk;
        unsigned one = 1;
        asm volatile("global_store_dword %0, %1, off sc0 sc1" :: "v"(fp), "v"(one) : "memory");
    }

    // per-wave constant h-fragment bases (kb offsets added as 64B imms)
    const u16* aB0 = hb0 + (size_t)(mt * 16 + c15) * Usz + kh * 256 + quad * 8;
    const u16* aB1 = hb1 + (size_t)(mt * 16 + c15) * Usz + kh * 256 + quad * 8;

    for (int t = 0; t < Tsz; ++t) {
        // ---- every wave polls all 64 flags (1/lane); own flag masked ----
        {
            const unsigned* fp1 = flags + ln;
            unsigned tgt = (unsigned)(t + 1);
            unsigned fv;
            do {
                asm volatile("global_load_dword %0, %1, off sc0 sc1\n\ts_waitcnt vmcnt(0)"
                             : "=v"(fv) : "v"(fp1) : "memory");
                if (ln == blk) fv = ~0u;
            } while (__any((int)(fv < tgt)));
        }

        float xv0 = xpn0, xv1 = xpn1, xv2 = xpn2, xv3 = xpn3;

        // ---- bypass-load this wave's h_{t-1} fragment (8 x 16B per lane) ----
        const u16* aBw = (t & 1) ? aB0 : aB1;
        short8 av[8];
#define LDH(i, OFF) asm volatile("global_load_dwordx4 %0, %1, off offset:" OFF " sc0 sc1" \
                                 : "=v"(av[i]) : "v"(aBw))
        LDH(0, "0");   LDH(1, "64");  LDH(2, "128"); LDH(3, "192");
        LDH(4, "256"); LDH(5, "320"); LDH(6, "384"); LDH(7, "448");
#undef LDH
        asm volatile("s_waitcnt vmcnt(0)" ::: "memory");
        __builtin_amdgcn_sched_barrier(0);

        // ---- MFMA: 4 independent acc chains (one per n-tile) ----
        f32x4 acc[4];
#pragma unroll
        for (int j = 0; j < 4; ++j) acc[j] = (f32x4){0.f, 0.f, 0.f, 0.f};
#pragma unroll
        for (int kbl = 0; kbl < 8; ++kbl)
#pragma unroll
            for (int j = 0; j < 4; ++j)
                acc[j] = __builtin_amdgcn_mfma_f32_16x16x32_bf16(av[kbl], rB[j * 8 + kbl], acc[j], 0, 0, 0);

        // prefetch next x_proj AFTER the A-drain: overlaps reduce/gates
        {
            int tn = (t + 1 < Tsz) ? t + 1 : t;
            size_t o = ((size_t)tn * 64 + blk) * 2048 + (size_t)b_row * 64 + (size_t)(ul * 4);
            if (xp32) { float4 v4 = *(const float4*)(xpf + o); xpn0 = v4.x; xpn1 = v4.y; xpn2 = v4.z; xpn3 = v4.w; }
            else      { u16x4 v = *(const u16x4*)(xph + o); xpn0 = bf2f(v[0]); xpn1 = bf2f(v[1]); xpn2 = bf2f(v[2]); xpn3 = bf2f(v[3]); }
        }

        // ---- kh-reduce through LDS ----
        if (kh > 0) {
#pragma unroll
            for (int j = 0; j < 4; ++j) partial[(kh - 1) * 2 + mt][j][ln] = acc[j];
        }
        __syncthreads();
        if (kh == 0) {
#pragma unroll
            for (int p = 0; p < 3; ++p)
#pragma unroll
                for (int j = 0; j < 4; ++j) acc[j] += partial[p * 2 + mt][j][ln];
            int gate = c15 >> 2, du = c15 & 3;
#pragma unroll
            for (int j = 0; j < 4; ++j) {
                int ulw = j * 4 + du;
#pragma unroll
                for (int r = 0; r < 4; ++r)
                    proj[((mt * 16 + quad * 4 + r) * 4 + gate) * 17 + ulw] = acc[j][r];
            }
        }
        __syncthreads();

        // ---- gates: every thread owns one (b,u) ----
        float ip = proj[(b_row * 4 + 0) * 17 + ul] + xv0 + bi0;
        float fp = proj[(b_row * 4 + 1) * 17 + ul] + xv1 + bi1;
        float op = proj[(b_row * 4 + 2) * 17 + ul] + xv2 + bi2;
        float zp = proj[(b_row * 4 + 3) * 17 + ul] + xv3 + bi3;
        float sf = 1.f / (1.f + __expf(-fp));
        float lf = __logf(sf + 1e-8f);
        float mn = fmaxf(ms + lf, ip);
        float it = __expf(ip - mn);
        float ft = __expf(ms + lf - mn);
        float ot = 1.f / (1.f + __expf(-op));
        float zt = tanhf(zp);
        cs = ft * cs + it * zt;
        ns = ft * ns + it;
        ms = mn;
        float h = ot * (cs / (ns + 1e-8f));
        out[(size_t)b_row * (Tsz * Usz) + (size_t)t * Usz + u_g] = h;   // plain (flushed at kernel end)
        u16* hp = ((t & 1) ? hb1 : hb0) + b_row * Usz + u_g;
        unsigned hv = (unsigned)f2bf(h);
        asm volatile("global_store_short %0, %1, off sc0 sc1" :: "v"(hp), "v"(hv) : "memory");
        asm volatile("s_waitcnt vmcnt(0)" ::: "memory");   // h stores ack'd in LLC
        __syncthreads();                                   // all waves drained
        if (tid == 0) {
            unsigned* fpw = flags + blk;
            unsigned val = (unsigned)(t + 2);
            asm volatile("global_store_dword %0, %1, off sc0 sc1" :: "v"(fpw), "v"(val) : "memory");
        }
    }
}

// =====================================================================
extern "C" void kernel_launch(void* const* d_in, const int* in_sizes, int n_in,
                              void* d_out, int out_size, void* d_ws, size_t ws_size,
                              hipStream_t stream) {
    const float* x    = (const float*)d_in[0];
    const float* W    = (const float*)d_in[1];
    const float* R    = (const float*)d_in[2];
    const float* bias = (const float*)d_in[3];
    float* out = (float*)d_out;

    char* ws = (char*)d_ws;
    size_t off = 0;
    u16* Af = (u16*)(ws + off); off += (size_t)16384 * 1024 * 2;  // 32MB
    u16* Bf = (u16*)(ws + off); off += (size_t)1024 * 4096 * 2;   // 8MB
    u16* Rp = (u16*)(ws + off); off += (size_t)1024 * 4096 * 2;   // 8MB
    u16* hbf = (u16*)(ws + off); off += (size_t)1 << 20;          // 1MB (2x64KB used)
    unsigned* flags = (unsigned*)(ws + off); off += 4096;         // 64 flags used
    size_t xp_need32 = (size_t)16384 * 4096 * 4;                  // 256MB
    int xp32 = (ws_size >= off + xp_need32) ? 1 : 0;
    float* xpf = (float*)(ws + off);
    u16*   xph = (u16*)(ws + off);

    pack_a<<<dim3(8192), dim3(256), 0, stream>>>(x, Af);
    pack_b<<<dim3(2048), dim3(256), 0, stream>>>(W, Bf);
    pack_r<<<dim3(2048), dim3(256), 0, stream>>>(R, Rp, flags);
    gemm1<<<dim3(4096), dim3(256), 0, stream>>>(Af, Bf, xpf, xph, xp32);

    void* args[] = { (void*)&xpf, (void*)&xph, (void*)&xp32, (void*)&Rp,
                     (void*)&bias, (void*)&hbf, (void*)&out, (void*)&flags };
    hipLaunchCooperativeKernel((const void*)scan_all, dim3(64), dim3(512), args, 0, stream);
}